// Round 4
// baseline (314.288 us; speedup 1.0000x reference)
//
#include <hip/hip_runtime.h>

// BasicBlock: y = relu(bn2(conv2(relu(bn1(conv1(x, we1))), we2)) + x)
// we{1,2} = sum_e alpha[e]*w{1,2}[e].
//
// All conv staging is linear global_load_lds (width 16) from a padded,
// chunk-swizzled NHWC bf16 image:
//   x_pad[b][114][114][64]  (in d_out; borders zeroed)
//   y1_pad[b][114][114][64] (in ws;    borders zeroed)
// Chunk swizzle: within each 128B pixel, 16B chunk slot = c8 ^ ((2h+w)&7)
// -> stride-128 ds_read_b128 A-fragment reads are bank-conflict-free.
//
// R4: latency-bound fix -> small blocks, many resident. 256 thr / 8x16 px
// tile / 22.5KB LDS -> 6-7 blocks/CU (vs 1.5 in R3). PASS1 epilogue is
// direct f32x4 global stores (D-frag rows are 4 consecutive w pixels).

typedef __bf16 bf16x8 __attribute__((ext_vector_type(8)));
typedef float f32x4 __attribute__((ext_vector_type(4)));
typedef unsigned short u16;
typedef u16 u16x8 __attribute__((ext_vector_type(8)));

#define NH 112
#define NW 112
#define PH 114
#define PW 114
#define PROWB (PW * 128)  // 14592 bytes per padded NHWC row

__device__ __forceinline__ u16 f2b(float f) {
  unsigned u = __builtin_bit_cast(unsigned, f);
  u += 0x7FFFu + ((u >> 16) & 1u);
  return (u16)(u >> 16);
}

__device__ __forceinline__ void gl_lds16(const void* g, void* l) {
  __builtin_amdgcn_global_load_lds(
      (const __attribute__((address_space(1))) unsigned int*)g,
      (__attribute__((address_space(3))) unsigned int*)l, 16, 0, 0);
}

// ---------------------------------------------------------------------------
// zero the 1-px borders of both padded buffers
__global__ void border_zero(u16* __restrict__ a, u16* __restrict__ bbuf) {
  int idx = blockIdx.x * 256 + threadIdx.x;  // 2*32*452*8 = 231424 chunks
  if (idx >= 231424) return;
  int c8 = idx & 7;
  int t = idx >> 3;
  int buf = t >= 14464;
  t -= buf * 14464;
  int img = t / 452, e = t % 452;
  int h, w;
  if (e < 114) { h = 0; w = e; }
  else if (e < 228) { h = 113; w = e - 114; }
  else if (e < 340) { h = e - 227; w = 0; }
  else { h = e - 339; w = 113; }
  u16* base = buf ? bbuf : a;
  u16x8 z = {0, 0, 0, 0, 0, 0, 0, 0};
  *reinterpret_cast<u16x8*>(base + (((long)img * PH + h) * PW + w) * 64 + c8 * 8) = z;
}

// ---------------------------------------------------------------------------
// x NCHW fp32 -> x_pad NHWC bf16 (padded + chunk-swizzled). block = (b,h).
__global__ __launch_bounds__(256) void transform_kernel(const float* __restrict__ x,
                                                        u16* __restrict__ xpad) {
  __shared__ alignas(16) u16 t[7168];  // [112 px][64 ch], xor-swizzled bytes
  int tid = threadIdx.x, bid = blockIdx.x;
  int b = bid / NH, h = bid % NH;
  const float* src = x + (long)b * 64 * 12544 + h * NW;
  f32x4 v[7];
#pragma unroll
  for (int it = 0; it < 7; ++it) {
    int fid = it * 256 + tid;  // 1792 = 64 ch * 28 quads
    int c = fid / 28, wq = fid % 28;
    v[it] = *reinterpret_cast<const f32x4*>(src + c * 12544 + wq * 4);
  }
#pragma unroll
  for (int it = 0; it < 7; ++it) {
    int fid = it * 256 + tid;
    int c = fid / 28, wq = fid % 28;
    int key = (wq & 7) << 4;
#pragma unroll
    for (int j = 0; j < 4; ++j) {
      int px = wq * 4 + j;
      *reinterpret_cast<u16*>((char*)t + px * 128 + ((c * 2) ^ key)) = f2b(v[it][j]);
    }
  }
  __syncthreads();
  int hp = h + 1;
  u16* rowb = xpad + (((long)b * PH + hp) * PW) * 64;
#pragma unroll
  for (int it = 0; it < 4; ++it) {
    int cidx = it * 256 + tid;
    if (cidx < 896) {  // 112 px * 8 chunks
      int c8 = cidx & 7, px = cidx >> 3;
      int lchunk = c8 ^ ((px >> 2) & 7);
      u16x8 vv = *reinterpret_cast<const u16x8*>((const char*)t + px * 128 + lchunk * 16);
      int wp = px + 1;
      int gkey = (2 * hp + wp) & 7;
      *reinterpret_cast<u16x8*>(rowb + (long)wp * 64 + ((c8 ^ gkey) * 8)) = vv;
    }
  }
}

// ---------------------------------------------------------------------------
// fold experts -> w_eff bf16 [kpos][o][i] + folded BN constants
__global__ void prep_kernel(
    const float* __restrict__ w1, const float* __restrict__ w2,
    const float* __restrict__ alpha,
    const float* __restrict__ g1, const float* __restrict__ b1,
    const float* __restrict__ m1, const float* __restrict__ v1,
    const float* __restrict__ g2, const float* __restrict__ b2,
    const float* __restrict__ m2, const float* __restrict__ v2,
    u16* __restrict__ weff1, u16* __restrict__ weff2, float* __restrict__ bnc) {
  int idx = blockIdx.x * 256 + threadIdx.x;  // 36864
  if (idx < 36864) {
    int i = idx & 63;
    int o = (idx >> 6) & 63;
    int kpos = idx >> 12;
    int base = (o * 64 + i) * 9 + kpos;  // src [E][O][I][3][3]
    float a1 = 0.f, a2 = 0.f;
#pragma unroll
    for (int e = 0; e < 10; ++e) {
      float al = alpha[e];
      a1 += al * w1[e * 36864 + base];
      a2 += al * w2[e * 36864 + base];
    }
    weff1[idx] = f2b(a1);
    weff2[idx] = f2b(a2);
  }
  if (blockIdx.x == 0 && threadIdx.x < 64) {
    int c = threadIdx.x;
    float i1 = g1[c] * rsqrtf(v1[c] + 1e-5f);
    float i2 = g2[c] * rsqrtf(v2[c] + 1e-5f);
    bnc[c] = i1;
    bnc[64 + c] = b1[c] - m1[c] * i1;
    bnc[128 + c] = i2;
    bnc[192 + c] = b2[c] - m2[c] * i2;
  }
}

// ---------------------------------------------------------------------------
// conv pass. 8x16 px x 64 oc per block, 256 threads (4 waves), grid 32*98.
// PASS 0: xin=x_pad -> bn1+relu -> y1_pad (swizzled NHWC bf16)
// PASS 1: xin=y1_pad -> bn2 + residual(x) + relu -> out (NCHW f32), direct
// ---------------------------------------------------------------------------
template <int PASS>
__global__ __launch_bounds__(256, 6) void conv_bn_kernel(
    const u16* __restrict__ xin, const float* __restrict__ x,
    const u16* __restrict__ weff, const float* __restrict__ bnc,
    u16* __restrict__ ypad, float* __restrict__ out) {
  __shared__ alignas(1024) char smem[23040];  // 10 rows * 18 px * 128 B

  int tid = threadIdx.x;
  int lane = tid & 63;
  int wv = tid >> 6;
  int bid = blockIdx.x;
  int b = bid / 98;
  int r = bid % 98;
  int h0 = (r / 7) * 8;   // multiple of 8 -> swizzle key needs only tile-local bits
  int w0 = (r % 7) * 16;  // multiple of 16

  // ---- stage 10x18 px window: pure linear global_load_lds (1440 chunks) ----
  const char* srcb = (const char*)(xin + (((long)b * PH + h0) * PW + w0) * 64);
#pragma unroll
  for (int c = 0; c < 6; ++c) {
    int idx = c * 256 + tid;
    if (idx < 1440) {
      int byte = idx * 16;
      int row = byte / 2304;  // 18 px * 128 B per tile row
      int rem = byte - row * 2304;
      gl_lds16(srcb + (long)row * PROWB + rem, smem + idx * 16);
    }
  }
  __syncthreads();

  // ---- MFMA: 9 kpos x 2 ksteps; wave owns Mfrags (2wv,2wv+1) x 4 Nfrags ----
  f32x4 acc[2][4];
#pragma unroll
  for (int mf = 0; mf < 2; ++mf)
#pragma unroll
    for (int nf = 0; nf < 4; ++nf) acc[mf][nf] = f32x4{0.f, 0.f, 0.f, 0.f};

  int ol = lane & 15;
  int kg = lane >> 4;
  int f0 = wv * 2;

#pragma unroll
  for (int kh = 0; kh < 3; ++kh)
#pragma unroll
    for (int kw = 0; kw < 3; ++kw) {
      int kpos = kh * 3 + kw;
#pragma unroll
      for (int ks = 0; ks < 2; ++ks) {
        bf16x8 bf[4];
#pragma unroll
        for (int nf = 0; nf < 4; ++nf) {
          const u16* p = weff + ((kpos * 64 + nf * 16 + ol) * 64 + ks * 32 + kg * 8);
          bf[nf] = __builtin_bit_cast(bf16x8, *reinterpret_cast<const u16x8*>(p));
        }
#pragma unroll
        for (int mf = 0; mf < 2; ++mf) {
          int rr = f0 + mf + kh;
          int col = ol + kw;
          int slot = ((ks << 2) | kg) ^ ((2 * rr + col) & 7);
          bf16x8 af =
              *reinterpret_cast<const bf16x8*>(smem + (rr * 18 + col) * 128 + slot * 16);
#pragma unroll
          for (int nf = 0; nf < 4; ++nf)
            acc[mf][nf] =
                __builtin_amdgcn_mfma_f32_16x16x32_bf16(af, bf[nf], acc[mf][nf], 0, 0, 0);
        }
      }
    }

  // ---- epilogue ----
  float inv[4], bias[4];
#pragma unroll
  for (int nf = 0; nf < 4; ++nf) {
    int o = nf * 16 + ol;
    inv[nf] = bnc[PASS * 128 + o];
    bias[nf] = bnc[PASS * 128 + 64 + o];
  }

  if constexpr (PASS == 0) {
    __syncthreads();  // done with A tile; reuse smem
    u16* ys = reinterpret_cast<u16*>(smem);  // [128 px][72]
#pragma unroll
    for (int mf = 0; mf < 2; ++mf)
#pragma unroll
      for (int nf = 0; nf < 4; ++nf) {
        int o = nf * 16 + ol;
#pragma unroll
        for (int rg = 0; rg < 4; ++rg) {
          int p = (f0 + mf) * 16 + kg * 4 + rg;
          ys[p * 72 + o] = f2b(fmaxf(acc[mf][nf][rg] * inv[nf] + bias[nf], 0.f));
        }
      }
    __syncthreads();
#pragma unroll
    for (int it = 0; it < 4; ++it) {
      int cidx = it * 256 + tid;  // 1024 chunks
      int c8 = cidx & 7, p = cidx >> 3;
      int hp = h0 + (p >> 4) + 1, wp = w0 + (p & 15) + 1;
      int gkey = (2 * hp + wp) & 7;
      *reinterpret_cast<u16x8*>(ypad + (((long)b * PH + hp) * PW + wp) * 64 +
                                ((c8 ^ gkey) * 8)) =
          *reinterpret_cast<const u16x8*>(ys + p * 72 + c8 * 8);
    }
  } else {
    // direct: lane's D-frag row rg holds pixel (h0+f0+mf, w0+kg*4+rg), oc=nf*16+ol
#pragma unroll
    for (int mf = 0; mf < 2; ++mf) {
      int h = h0 + f0 + mf;
      f32x4 xr[4];
#pragma unroll
      for (int nf = 0; nf < 4; ++nf) {
        int gi = ((b * 64 + nf * 16 + ol) * NH + h) * NW + w0 + kg * 4;
        xr[nf] = *reinterpret_cast<const f32x4*>(x + gi);
      }
#pragma unroll
      for (int nf = 0; nf < 4; ++nf) {
        int gi = ((b * 64 + nf * 16 + ol) * NH + h) * NW + w0 + kg * 4;
        f32x4 vv;
#pragma unroll
        for (int rg = 0; rg < 4; ++rg)
          vv[rg] = fmaxf(acc[mf][nf][rg] * inv[nf] + bias[nf] + xr[nf][rg], 0.f);
        *reinterpret_cast<f32x4*>(out + gi) = vv;
      }
    }
  }
}

// ---------------------------------------------------------------------------
extern "C" void kernel_launch(void* const* d_in, const int* in_sizes, int n_in,
                              void* d_out, int out_size, void* d_ws, size_t ws_size,
                              hipStream_t stream) {
  const float* x = (const float*)d_in[0];
  const float* w1 = (const float*)d_in[1];
  const float* w2 = (const float*)d_in[2];
  const float* alpha = (const float*)d_in[3];
  const float* g1 = (const float*)d_in[4];
  const float* b1 = (const float*)d_in[5];
  const float* m1 = (const float*)d_in[6];
  const float* v1 = (const float*)d_in[7];
  const float* g2 = (const float*)d_in[8];
  const float* b2 = (const float*)d_in[9];
  const float* m2 = (const float*)d_in[10];
  const float* v2 = (const float*)d_in[11];
  float* out = (float*)d_out;

  char* ws = (char*)d_ws;
  u16* weff1 = (u16*)ws;                 // 73728 B
  u16* weff2 = (u16*)(ws + 73728);       // 73728 B
  float* bnc = (float*)(ws + 147456);    // 1024 B
  u16* y1pad = (u16*)(ws + 148480);      // 32*114*114*64*2 = 53231616 B
  u16* xpad = (u16*)d_out;               // 53231616 B <= 102760448 B; dead by pass 1

  border_zero<<<904, 256, 0, stream>>>(xpad, y1pad);
  transform_kernel<<<32 * NH, 256, 0, stream>>>(x, xpad);
  prep_kernel<<<144, 256, 0, stream>>>(w1, w2, alpha, g1, b1, m1, v1,
                                       g2, b2, m2, v2, weff1, weff2, bnc);
  conv_bn_kernel<0><<<3136, 256, 0, stream>>>(xpad, x, weff1, bnc, y1pad, nullptr);
  conv_bn_kernel<1><<<3136, 256, 0, stream>>>(y1pad, x, weff2, bnc, nullptr, out);
}

// Round 6
// 155.461 us; speedup vs baseline: 2.0217x; 2.0217x over previous
//
#include <hip/hip_runtime.h>

// BasicBlock: y = relu(bn2(conv2(relu(bn1(conv1(x, we1))), we2)) + x)
// we{1,2} = sum_e alpha[e]*w{1,2}[e].
//
// bf16 implicit-GEMM conv, mfma_f32_16x16x32_bf16, staged from padded,
// chunk-swizzled NHWC bf16 images (slot = c8 ^ ((2h+w)&7) within 128B px).
//
// R6 = R5 with the vmcnt race fixed:
//  - t=0 gate: wait vmcnt(6/5) where the ONLY younger VMEM ops are stage1's
//    loads (loads are oldest-first ordered -> sound).
//  - stage1 drain: vmcnt(0) at END of compute(t0), before any epilogue VMEM
//    (loads-only window; nearly free since compute(t0) covered the latency).
//    R5 gated t=1 after the epilogue with mixed loads+stores in the younger
//    window -> unsound (and for PASS1 the count was so large it never waited).
// Weights preloaded to registers (36 bf16x8/wave) so the K-loop has zero VMEM.

typedef __bf16 bf16x8 __attribute__((ext_vector_type(8)));
typedef float f32x4 __attribute__((ext_vector_type(4)));
typedef unsigned short u16;
typedef u16 u16x8 __attribute__((ext_vector_type(8)));

#define NH 112
#define NW 112
#define PH 114
#define PW 114
#define PROWB (PW * 128)  // 14592 bytes per padded NHWC row
#define BUFB 23040        // one A-tile buffer: 10 rows * 18 px * 128 B

__device__ __forceinline__ u16 f2b(float f) {
  unsigned u = __builtin_bit_cast(unsigned, f);
  u += 0x7FFFu + ((u >> 16) & 1u);
  return (u16)(u >> 16);
}

__device__ __forceinline__ void gl_lds16(const void* g, void* l) {
  __builtin_amdgcn_global_load_lds(
      (const __attribute__((address_space(1))) unsigned int*)g,
      (__attribute__((address_space(3))) unsigned int*)l, 16, 0, 0);
}

// ---------------------------------------------------------------------------
__global__ void border_zero(u16* __restrict__ a, u16* __restrict__ bbuf) {
  int idx = blockIdx.x * 256 + threadIdx.x;  // 2*32*452*8 = 231424 chunks
  if (idx >= 231424) return;
  int c8 = idx & 7;
  int t = idx >> 3;
  int buf = t >= 14464;
  t -= buf * 14464;
  int img = t / 452, e = t % 452;
  int h, w;
  if (e < 114) { h = 0; w = e; }
  else if (e < 228) { h = 113; w = e - 114; }
  else if (e < 340) { h = e - 227; w = 0; }
  else { h = e - 339; w = 113; }
  u16* base = buf ? bbuf : a;
  u16x8 z = {0, 0, 0, 0, 0, 0, 0, 0};
  *reinterpret_cast<u16x8*>(base + (((long)img * PH + h) * PW + w) * 64 + c8 * 8) = z;
}

// ---------------------------------------------------------------------------
// x NCHW fp32 -> x_pad NHWC bf16 (padded + chunk-swizzled). block = (b,h).
__global__ __launch_bounds__(256) void transform_kernel(const float* __restrict__ x,
                                                        u16* __restrict__ xpad) {
  __shared__ alignas(16) u16 t[7168];  // [112 px][64 ch], xor-swizzled bytes
  int tid = threadIdx.x, bid = blockIdx.x;
  int b = bid / NH, h = bid % NH;
  const float* src = x + (long)b * 64 * 12544 + h * NW;
  f32x4 v[7];
#pragma unroll
  for (int it = 0; it < 7; ++it) {
    int fid = it * 256 + tid;  // 1792 = 64 ch * 28 quads
    int c = fid / 28, wq = fid % 28;
    v[it] = *reinterpret_cast<const f32x4*>(src + c * 12544 + wq * 4);
  }
#pragma unroll
  for (int it = 0; it < 7; ++it) {
    int fid = it * 256 + tid;
    int c = fid / 28, wq = fid % 28;
    int key = (wq & 7) << 4;
#pragma unroll
    for (int j = 0; j < 4; ++j) {
      int px = wq * 4 + j;
      *reinterpret_cast<u16*>((char*)t + px * 128 + ((c * 2) ^ key)) = f2b(v[it][j]);
    }
  }
  __syncthreads();
  int hp = h + 1;
  u16* rowb = xpad + (((long)b * PH + hp) * PW) * 64;
#pragma unroll
  for (int it = 0; it < 4; ++it) {
    int cidx = it * 256 + tid;
    if (cidx < 896) {  // 112 px * 8 chunks
      int c8 = cidx & 7, px = cidx >> 3;
      int lchunk = c8 ^ ((px >> 2) & 7);
      u16x8 vv = *reinterpret_cast<const u16x8*>((const char*)t + px * 128 + lchunk * 16);
      int wp = px + 1;
      int gkey = (2 * hp + wp) & 7;
      *reinterpret_cast<u16x8*>(rowb + (long)wp * 64 + ((c8 ^ gkey) * 8)) = vv;
    }
  }
}

// ---------------------------------------------------------------------------
// fold experts -> w_eff bf16 [kpos][o][i] + folded BN constants
__global__ void prep_kernel(
    const float* __restrict__ w1, const float* __restrict__ w2,
    const float* __restrict__ alpha,
    const float* __restrict__ g1, const float* __restrict__ b1,
    const float* __restrict__ m1, const float* __restrict__ v1,
    const float* __restrict__ g2, const float* __restrict__ b2,
    const float* __restrict__ m2, const float* __restrict__ v2,
    u16* __restrict__ weff1, u16* __restrict__ weff2, float* __restrict__ bnc) {
  int idx = blockIdx.x * 256 + threadIdx.x;  // 36864
  if (idx < 36864) {
    int i = idx & 63;
    int o = (idx >> 6) & 63;
    int kpos = idx >> 12;
    int base = (o * 64 + i) * 9 + kpos;  // src [E][O][I][3][3]
    float a1 = 0.f, a2 = 0.f;
#pragma unroll
    for (int e = 0; e < 10; ++e) {
      float al = alpha[e];
      a1 += al * w1[e * 36864 + base];
      a2 += al * w2[e * 36864 + base];
    }
    weff1[idx] = f2b(a1);
    weff2[idx] = f2b(a2);
  }
  if (blockIdx.x == 0 && threadIdx.x < 64) {
    int c = threadIdx.x;
    float i1 = g1[c] * rsqrtf(v1[c] + 1e-5f);
    float i2 = g2[c] * rsqrtf(v2[c] + 1e-5f);
    bnc[c] = i1;
    bnc[64 + c] = b1[c] - m1[c] * i1;
    bnc[128 + c] = i2;
    bnc[192 + c] = b2[c] - m2[c] * i2;
  }
}

// ---------------------------------------------------------------------------
// conv pass. 8x16 px x 64 oc per tile, 2 tiles/block (double-buffered),
// 256 threads (4 waves: wave = 4 Mfrags(rows) x 2 Nfrags), grid 1568.
// PASS 0: xin=x_pad -> bn1+relu -> y1_pad (swizzled NHWC bf16)
// PASS 1: xin=y1_pad -> bn2 + residual(x) + relu -> out (NCHW f32)
// ---------------------------------------------------------------------------
template <int PASS>
__global__ __launch_bounds__(256, 2) void conv_bn_kernel(
    const u16* __restrict__ xin, const float* __restrict__ x,
    const u16* __restrict__ weff, const float* __restrict__ bnc,
    u16* __restrict__ ypad, float* __restrict__ out) {
  __shared__ alignas(64) char smem[2 * BUFB];

  int tid = threadIdx.x, lane = tid & 63, wv = tid >> 6;
  int ol = lane & 15, kg = (lane >> 4) & 3;
  int f0 = (wv >> 1) * 4, nf0 = (wv & 1) * 2;

  // ---- BN consts + weights -> registers; drain so the K-loop has no VMEM ----
  float inv[2], bias[2];
#pragma unroll
  for (int j = 0; j < 2; ++j) {
    int o = (nf0 + j) * 16 + ol;
    inv[j] = bnc[PASS * 128 + o];
    bias[j] = bnc[PASS * 128 + 64 + o];
  }
  bf16x8 wf[3][3][2][2];  // [kh][kw][ks][nf-local]
#pragma unroll
  for (int kh = 0; kh < 3; ++kh)
#pragma unroll
    for (int kw = 0; kw < 3; ++kw)
#pragma unroll
      for (int ks = 0; ks < 2; ++ks)
#pragma unroll
        for (int j = 0; j < 2; ++j)
          wf[kh][kw][ks][j] = __builtin_bit_cast(
              bf16x8, *reinterpret_cast<const u16x8*>(
                          weff + (((kh * 3 + kw) * 64 + (nf0 + j) * 16 + ol) * 64 +
                                  ks * 32 + kg * 8)));
  asm volatile("s_waitcnt vmcnt(0)" ::: "memory");
  __builtin_amdgcn_sched_barrier(0);

  // ---- tile decode (XCD-chunked swizzle; 1568 = 8*196 bijective) ----
  int sb = (blockIdx.x & 7) * 196 + (blockIdx.x >> 3);
  int tb[2], th0[2], tw0[2];
#pragma unroll
  for (int t = 0; t < 2; ++t) {
    int tt = sb * 2 + t;
    tb[t] = tt / 98;
    int r = tt % 98;
    th0[t] = (r / 7) * 8;
    tw0[t] = (r % 7) * 16;
  }

  // stage one 10x18 window (1440 chunks; waves issue 6,6,6,5 insts)
  auto stage = [&](int t, int boff) {
#pragma unroll
    for (int k = 0; k < 6; ++k) {
      int i = wv + k * 4;
      if (i < 23) {
        int cb = i * 64 + lane;
        if (cb < 1440) {
          int row = cb / 144, rem = cb % 144;
          gl_lds16((const char*)(xin + (((long)tb[t] * PH + th0[t]) * PW + tw0[t]) * 64) +
                       (long)row * PROWB + rem * 16,
                   smem + boff + cb * 16);
        }
      }
    }
  };

  stage(0, 0);
  asm volatile("" ::: "memory");  // keep stage0 | stage1 issue groups ordered
  stage(1, BUFB);                 // in flight across compute(t0)
  asm volatile("" ::: "memory");
  // own stage0 done: younger ops = own stage1 = 6 loads (wave3: 5), loads-only
  if (wv < 3) asm volatile("s_waitcnt vmcnt(6)" ::: "memory");
  else        asm volatile("s_waitcnt vmcnt(5)" ::: "memory");
  __builtin_amdgcn_sched_barrier(0);

#pragma unroll
  for (int t = 0; t < 2; ++t) {
    const int boff = t * BUFB;
    __builtin_amdgcn_s_barrier();  // all waves' tile-t data landed & visible
    __builtin_amdgcn_sched_barrier(0);

    // ---- MFMA: per (kw,ks) load 6 row-frags, 24 MFMA reusing them ----
    f32x4 acc[4][2];
#pragma unroll
    for (int mf = 0; mf < 4; ++mf)
#pragma unroll
      for (int j = 0; j < 2; ++j) acc[mf][j] = f32x4{0.f, 0.f, 0.f, 0.f};

#pragma unroll
    for (int kw = 0; kw < 3; ++kw)
#pragma unroll
      for (int ks = 0; ks < 2; ++ks) {
        bf16x8 a[6];
#pragma unroll
        for (int u = 0; u < 6; ++u) {
          int rr = f0 + u, col = ol + kw;
          int slot = ((ks << 2) | kg) ^ ((2 * rr + col) & 7);
          a[u] = *reinterpret_cast<const bf16x8*>(smem + boff +
                                                  (rr * 18 + col) * 128 + slot * 16);
        }
#pragma unroll
        for (int kh = 0; kh < 3; ++kh)
#pragma unroll
          for (int mf = 0; mf < 4; ++mf)
#pragma unroll
            for (int j = 0; j < 2; ++j)
              acc[mf][j] = __builtin_amdgcn_mfma_f32_16x16x32_bf16(
                  a[mf + kh], wf[kh][kw][ks][j], acc[mf][j], 0, 0, 0);
      }

    if (t == 0) {
      // drain stage1 (loads-only window; latency covered by compute above)
      asm volatile("s_waitcnt vmcnt(0)" ::: "memory");
      __builtin_amdgcn_sched_barrier(0);
    }

    // ---- epilogue ----
    if constexpr (PASS == 0) {
      __builtin_amdgcn_sched_barrier(0);
      __builtin_amdgcn_s_barrier();  // all waves done reading buf[t]: reuse it
      __builtin_amdgcn_sched_barrier(0);
      u16* ys = reinterpret_cast<u16*>(smem + boff);  // [128 px][72]
#pragma unroll
      for (int mf = 0; mf < 4; ++mf)
#pragma unroll
        for (int j = 0; j < 2; ++j) {
          int o = (nf0 + j) * 16 + ol;
#pragma unroll
          for (int rg = 0; rg < 4; ++rg) {
            int p = (f0 + mf) * 16 + kg * 4 + rg;
            ys[p * 72 + o] = f2b(fmaxf(acc[mf][j][rg] * inv[j] + bias[j], 0.f));
          }
        }
      asm volatile("s_waitcnt lgkmcnt(0)" ::: "memory");
      __builtin_amdgcn_sched_barrier(0);
      __builtin_amdgcn_s_barrier();
      __builtin_amdgcn_sched_barrier(0);
#pragma unroll
      for (int it = 0; it < 4; ++it) {
        int cidx = it * 256 + tid;  // 1024 chunks
        int c8 = cidx & 7, p = cidx >> 3;
        int hp = th0[t] + (p >> 4) + 1, wp = tw0[t] + (p & 15) + 1;
        int gkey = (2 * hp + wp) & 7;
        *reinterpret_cast<u16x8*>(ypad + (((long)tb[t] * PH + hp) * PW + wp) * 64 +
                                  ((c8 ^ gkey) * 8)) =
            *reinterpret_cast<const u16x8*>(ys + p * 72 + c8 * 8);
      }
    } else {
      // direct: D-frag row rg = pixel (th0+f0+mf, tw0+kg*4+rg), oc = nf*16+ol
#pragma unroll
      for (int half = 0; half < 2; ++half) {
        f32x4 xr[2][2];
#pragma unroll
        for (int m = 0; m < 2; ++m) {
          int h = th0[t] + f0 + half * 2 + m;
#pragma unroll
          for (int j = 0; j < 2; ++j)
            xr[m][j] = *reinterpret_cast<const f32x4*>(
                x + (((tb[t] * 64 + (nf0 + j) * 16 + ol) * NH + h) * NW + tw0[t] +
                     kg * 4));
        }
#pragma unroll
        for (int m = 0; m < 2; ++m) {
          int mf = half * 2 + m;
          int h = th0[t] + f0 + mf;
#pragma unroll
          for (int j = 0; j < 2; ++j) {
            f32x4 vv;
#pragma unroll
            for (int rg = 0; rg < 4; ++rg)
              vv[rg] = fmaxf(acc[mf][j][rg] * inv[j] + bias[j] + xr[m][j][rg], 0.f);
            *reinterpret_cast<f32x4*>(
                out + (((tb[t] * 64 + (nf0 + j) * 16 + ol) * NH + h) * NW + tw0[t] +
                       kg * 4)) = vv;
          }
        }
      }
    }
  }
}

// ---------------------------------------------------------------------------
extern "C" void kernel_launch(void* const* d_in, const int* in_sizes, int n_in,
                              void* d_out, int out_size, void* d_ws, size_t ws_size,
                              hipStream_t stream) {
  const float* x = (const float*)d_in[0];
  const float* w1 = (const float*)d_in[1];
  const float* w2 = (const float*)d_in[2];
  const float* alpha = (const float*)d_in[3];
  const float* g1 = (const float*)d_in[4];
  const float* b1 = (const float*)d_in[5];
  const float* m1 = (const float*)d_in[6];
  const float* v1 = (const float*)d_in[7];
  const float* g2 = (const float*)d_in[8];
  const float* b2 = (const float*)d_in[9];
  const float* m2 = (const float*)d_in[10];
  const float* v2 = (const float*)d_in[11];
  float* out = (float*)d_out;

  char* ws = (char*)d_ws;
  u16* weff1 = (u16*)ws;                 // 73728 B
  u16* weff2 = (u16*)(ws + 73728);       // 73728 B
  float* bnc = (float*)(ws + 147456);    // 1024 B
  u16* y1pad = (u16*)(ws + 148480);      // 32*114*114*64*2 = 53231616 B
  u16* xpad = (u16*)d_out;               // 53 MB <= 103 MB; dead before P1 writes

  border_zero<<<904, 256, 0, stream>>>(xpad, y1pad);
  transform_kernel<<<32 * NH, 256, 0, stream>>>(x, xpad);
  prep_kernel<<<144, 256, 0, stream>>>(w1, w2, alpha, g1, b1, m1, v1,
                                       g2, b2, m2, v2, weff1, weff2, bnc);
  conv_bn_kernel<0><<<1568, 256, 0, stream>>>(xpad, x, weff1, bnc, y1pad, nullptr);
  conv_bn_kernel<1><<<1568, 256, 0, stream>>>(y1pad, x, weff2, bnc, nullptr, out);
}